// Round 1
// baseline (3050.229 us; speedup 1.0000x reference)
//
#include <hip/hip_runtime.h>
#include <stdint.h>

// ---------------- problem constants ----------------
#define T_TOK 8192
#define HDIM  2048
#define IDIM  1024
#define NEXP  64
#define KTOP  8
#define TGRP  4
#define TKTOT (T_TOK*KTOP)   // 65536
#define MAXTILES 1024
#define RSCALE 2.5f

typedef __attribute__((ext_vector_type(8))) short short8;
typedef __attribute__((ext_vector_type(4))) float f32x4;

__device__ __forceinline__ float bf2f(uint16_t u) {
    union { unsigned i; float f; } v; v.i = ((unsigned)u) << 16; return v.f;
}
__device__ __forceinline__ uint16_t f2bf(float f) {
    union { float f; unsigned i; } v; v.f = f;
    unsigned r = (v.i + 0x7FFFu + ((v.i >> 16) & 1u)) >> 16;
    return (uint16_t)r;
}
__device__ __forceinline__ void gload_lds16(const void* g, void* l) {
    __builtin_amdgcn_global_load_lds(
        (const __attribute__((address_space(1))) void*)g,
        (__attribute__((address_space(3))) void*)l, 16, 0, 0);
}
__device__ __forceinline__ int imin(int a, int b) { return a < b ? a : b; }

// ---------------- router + grouped topk ----------------
// block: 256 thr (4 waves); handles 16 tokens x 64 experts. fp32 exact.
__global__ __launch_bounds__(256) void k_router(
    const float* __restrict__ x, const float* __restrict__ gw,
    const float* __restrict__ ebias,
    int* __restrict__ topk_ids, float* __restrict__ topk_w,
    int* __restrict__ counts)
{
    __shared__ float xs[16][132];
    __shared__ float wsb[64][133];
    __shared__ float sc[16][65];   // biased scores
    __shared__ float su[16][65];   // unbiased sigmoid
    const int tid = threadIdx.x;
    const int e = tid & 63;
    const int tg = tid >> 6;          // wave id 0..3
    const long tblk = (long)blockIdx.x * 16;

    float acc0 = 0.f, acc1 = 0.f, acc2 = 0.f, acc3 = 0.f;
    for (int ch = 0; ch < 16; ++ch) {
        const int h0 = ch << 7;
        for (int i = tid; i < 512; i += 256) {       // 16x128 floats as float4
            int r = i >> 5, c4 = (i & 31) << 2;
            float4 v = *(const float4*)(x + (tblk + r) * HDIM + h0 + c4);
            *(float4*)&xs[r][c4] = v;
        }
        for (int i = tid; i < 8192; i += 256) {      // 64x128 floats
            int r = i >> 7, c = i & 127;
            wsb[r][c] = gw[(long)r * HDIM + h0 + c];
        }
        __syncthreads();
        #pragma unroll 8
        for (int hh = 0; hh < 128; ++hh) {
            float wv = wsb[e][hh];
            acc0 += xs[tg][hh] * wv;
            acc1 += xs[tg + 4][hh] * wv;
            acc2 += xs[tg + 8][hh] * wv;
            acc3 += xs[tg + 12][hh] * wv;
        }
        __syncthreads();
    }
    const float be = ebias[e];
    {
        float s;
        s = 1.f / (1.f + expf(-acc0)); su[tg][e] = s;      sc[tg][e] = s + be;
        s = 1.f / (1.f + expf(-acc1)); su[tg + 4][e] = s;  sc[tg + 4][e] = s + be;
        s = 1.f / (1.f + expf(-acc2)); su[tg + 8][e] = s;  sc[tg + 8][e] = s + be;
        s = 1.f / (1.f + expf(-acc3)); su[tg + 12][e] = s; sc[tg + 12][e] = s + be;
    }
    __syncthreads();
    if (tid < 16) {
        const int t = tid;
        float gs[8];
        #pragma unroll
        for (int g = 0; g < 8; ++g) {
            float m1 = -1e30f, m2 = -1e30f;
            #pragma unroll
            for (int j = 0; j < 8; ++j) {
                float v = sc[t][g * 8 + j];
                if (v > m1) { m2 = m1; m1 = v; } else if (v > m2) { m2 = v; }
            }
            gs[g] = m1 + m2;
        }
        int selmask = 0;
        #pragma unroll
        for (int it = 0; it < TGRP; ++it) {
            float best = -1e30f; int bg = 0;
            #pragma unroll
            for (int g = 0; g < 8; ++g)
                if (!((selmask >> g) & 1) && gs[g] > best) { best = gs[g]; bg = g; }
            selmask |= (1 << bg);
        }
        unsigned long long chosen = 0ull;
        int ids[KTOP]; float wv[KTOP]; float wsum = 0.f;
        #pragma unroll
        for (int it = 0; it < KTOP; ++it) {
            float best = -1e30f; int bi = 0;
            for (int ee = 0; ee < 64; ++ee) {
                if (((selmask >> (ee >> 3)) & 1) && !((chosen >> ee) & 1ull)) {
                    float v = sc[t][ee];
                    if (v > best) { best = v; bi = ee; }
                }
            }
            chosen |= (1ull << bi);
            ids[it] = bi; wv[it] = su[t][bi]; wsum += wv[it];
        }
        const float inv = 1.f / wsum;
        #pragma unroll
        for (int k = 0; k < KTOP; ++k) {
            topk_ids[(tblk + t) * KTOP + k] = ids[k];
            topk_w[(tblk + t) * KTOP + k] = wv[k] * inv;
            atomicAdd(&counts[ids[k]], 1);
        }
    }
}

// ---------------- offsets + tile map (serial, tiny) ----------------
__global__ void k_scan(const int* __restrict__ counts, int* offsets, int* cursor,
                       int* tile_e, int* tile_r0, int* tile_end, int* ntiles)
{
    if (threadIdx.x || blockIdx.x) return;
    int off = 0, nt = 0;
    for (int e = 0; e < NEXP; ++e) {
        offsets[e] = off; cursor[e] = off;
        int c = counts[e];
        for (int m0 = 0; m0 < c; m0 += 128) {
            tile_e[nt] = e; tile_r0[nt] = off + m0; tile_end[nt] = off + c; ++nt;
        }
        off += c;
    }
    *ntiles = nt;
}

__global__ __launch_bounds__(256) void k_scatter(
    const int* __restrict__ topk_ids, int* cursor,
    int* __restrict__ perm_token, int* __restrict__ slot_of)
{
    int i = blockIdx.x * 256 + threadIdx.x;
    if (i >= TKTOT) return;
    int e = topk_ids[i];
    int pos = atomicAdd(&cursor[e], 1);
    perm_token[pos] = i >> 3;
    slot_of[i] = pos;
}

// ---------------- fp32 -> bf16 elementwise ----------------
__global__ __launch_bounds__(256) void k_cvt_bf16(
    const float* __restrict__ in, uint16_t* __restrict__ outp, long n4)
{
    long i = (long)blockIdx.x * 256 + threadIdx.x;
    if (i >= n4) return;
    float4 v = *(const float4*)(in + i * 4);
    uint64_t pk = (uint64_t)f2bf(v.x) | ((uint64_t)f2bf(v.y) << 16)
                | ((uint64_t)f2bf(v.z) << 32) | ((uint64_t)f2bf(v.w) << 48);
    *(uint64_t*)(outp + i * 4) = pk;
}

// ---------------- tiled transpose + cvt: src f32 [R][C] -> dst bf16 [C'][R] ----------------
// INTER: gate/up row interleave c -> 2*(c&1023) + (c>>10)
template<bool INTER>
__global__ __launch_bounds__(256) void k_transpose(
    const float* __restrict__ src, uint16_t* __restrict__ dst,
    int R, int C, long sStride, long dStride)
{
    __shared__ float tile[32][33];
    const int c0 = blockIdx.x << 5, r0 = blockIdx.y << 5, s = blockIdx.z;
    const float* S = src + (long)s * sStride;
    uint16_t* D = dst + (long)s * dStride;
    const int xi = threadIdx.x & 31;
    const int y0 = threadIdx.x >> 5;
    #pragma unroll
    for (int i = 0; i < 4; ++i) {
        int y = y0 + i * 8;
        tile[y][xi] = S[(long)(r0 + y) * C + c0 + xi];
    }
    __syncthreads();
    #pragma unroll
    for (int i = 0; i < 4; ++i) {
        int y = y0 + i * 8;
        int c = c0 + y;
        int rd = INTER ? (((c & (IDIM - 1)) << 1) + (c >> 10)) : c;
        D[(long)rd * R + r0 + xi] = f2bf(tile[xi][y]);
    }
}

// ---------------- MFMA GEMM: 128x128 tile, BK=32, 4 waves, 16x16x32 bf16 ----------------
// A [rows][Kd] bf16 (row-gathered if GATEUP&&ROUTED); B [2048 rows][Kd] bf16 (pre-transposed)
// GATEUP: interleaved gate/up cols, epilogue silu(g)*u -> bf16 [rows][IDIM]
// !GATEUP && ROUTED: -> bf16 y [slot][HDIM]; !GATEUP && !ROUTED: -> f32 d_out [t][HDIM]
template<bool GATEUP, bool ROUTED>
__global__ __launch_bounds__(256) void k_gemm(
    const uint16_t* __restrict__ A, const uint16_t* __restrict__ Bw,
    void* __restrict__ OutP,
    const int* __restrict__ perm_token,
    const int* __restrict__ tile_e, const int* __restrict__ tile_r0,
    const int* __restrict__ tile_end, const int* __restrict__ ntiles,
    int Kd, long expStride)
{
    __shared__ uint16_t As[128 * 32];
    __shared__ uint16_t Bs[128 * 32];
    const int tid = threadIdx.x;
    const int wid = tid >> 6, lane = tid & 63;

    int row0, segEnd; long eoff;
    if (ROUTED) {
        int tt = blockIdx.x;
        if (tt >= *ntiles) return;
        row0 = tile_r0[tt]; segEnd = tile_end[tt];
        eoff = (long)tile_e[tt] * expStride;
    } else {
        row0 = blockIdx.x << 7; segEnd = row0 + 128; eoff = 0;
    }
    const int n0 = blockIdx.y << 7;
    const uint16_t* Bbase = Bw + eoff;

    // staging: each wave stages 2 chunks of 1024B for A and B (lane*16B each)
    const int o0 = wid * 2048 + lane * 16;          // byte offset in 8KB tile
    const int ra0 = o0 >> 6, ra1 = (o0 + 1024) >> 6; // local row (64B rows)
    const int kb = (o0 & 63) >> 1;                   // element offset within row
    const uint16_t *pa0, *pa1;
    if (GATEUP && ROUTED) {
        int s0 = imin(row0 + ra0, segEnd - 1), s1 = imin(row0 + ra1, segEnd - 1);
        pa0 = A + (long)perm_token[s0] * Kd + kb;
        pa1 = A + (long)perm_token[s1] * Kd + kb;
    } else if (ROUTED) {
        int s0 = imin(row0 + ra0, segEnd - 1), s1 = imin(row0 + ra1, segEnd - 1);
        pa0 = A + (long)s0 * Kd + kb;
        pa1 = A + (long)s1 * Kd + kb;
    } else {
        pa0 = A + (long)(row0 + ra0) * Kd + kb;
        pa1 = A + (long)(row0 + ra1) * Kd + kb;
    }
    const uint16_t* pb0 = Bbase + (long)(n0 + ra0) * Kd + kb;
    const uint16_t* pb1 = Bbase + (long)(n0 + ra1) * Kd + kb;
    uint16_t* AsW = As + wid * 1024;
    uint16_t* BsW = Bs + wid * 1024;

    const int wm = wid >> 1, wn = wid & 1;
    const uint16_t* AsR = As + (wm * 64 + (lane & 15)) * 32 + ((lane >> 4) << 3);
    const uint16_t* BsR = Bs + (wn * 64 + (lane & 15)) * 32 + ((lane >> 4) << 3);

    f32x4 acc[4][4];
    #pragma unroll
    for (int i = 0; i < 4; ++i)
        #pragma unroll
        for (int j = 0; j < 4; ++j) {
            f32x4 z = {0.f, 0.f, 0.f, 0.f};
            acc[i][j] = z;
        }

    const int nK = Kd >> 5;
    for (int kt = 0; kt < nK; ++kt) {
        gload_lds16(pa0, AsW);
        gload_lds16(pa1, AsW + 512);
        gload_lds16(pb0, BsW);
        gload_lds16(pb1, BsW + 512);
        pa0 += 32; pa1 += 32; pb0 += 32; pb1 += 32;
        __syncthreads();   // drains vmcnt (compiler) -> LDS tile ready
        short8 af[4], bfr[4];
        #pragma unroll
        for (int f = 0; f < 4; ++f) af[f] = *(const short8*)(AsR + f * 512);
        #pragma unroll
        for (int f = 0; f < 4; ++f) bfr[f] = *(const short8*)(BsR + f * 512);
        #pragma unroll
        for (int fm = 0; fm < 4; ++fm)
            #pragma unroll
            for (int fn = 0; fn < 4; ++fn)
                acc[fm][fn] = __builtin_amdgcn_mfma_f32_16x16x32_bf16(
                    af[fm], bfr[fn], acc[fm][fn], 0, 0, 0);
        __syncthreads();   // protect LDS before next stage
    }

    const int colb = n0 + wn * 64 + (lane & 15);
    const int rowb = row0 + wm * 64 + ((lane >> 4) << 2);
    if (GATEUP) {
        uint16_t* Oact = (uint16_t*)OutP;
        const bool evenl = ((lane & 1) == 0);
        #pragma unroll
        for (int fm = 0; fm < 4; ++fm)
            #pragma unroll
            for (int fn = 0; fn < 4; ++fn) {
                f32x4 v = acc[fm][fn];
                #pragma unroll
                for (int r = 0; r < 4; ++r) {
                    float g = v[r];
                    float u = __shfl_xor(g, 1, 64);
                    int row = rowb + fm * 16 + r;
                    if (evenl && (!ROUTED || row < segEnd)) {
                        int j = (colb + fn * 16) >> 1;
                        float sg = g / (1.f + expf(-g));
                        Oact[(long)row * IDIM + j] = f2bf(sg * u);
                    }
                }
            }
    } else if (ROUTED) {
        uint16_t* Y = (uint16_t*)OutP;
        #pragma unroll
        for (int fm = 0; fm < 4; ++fm)
            #pragma unroll
            for (int fn = 0; fn < 4; ++fn) {
                f32x4 v = acc[fm][fn];
                #pragma unroll
                for (int r = 0; r < 4; ++r) {
                    int row = rowb + fm * 16 + r;
                    if (row < segEnd)
                        Y[(long)row * HDIM + colb + fn * 16] = f2bf(v[r]);
                }
            }
    } else {
        float* O = (float*)OutP;
        #pragma unroll
        for (int fm = 0; fm < 4; ++fm)
            #pragma unroll
            for (int fn = 0; fn < 4; ++fn) {
                f32x4 v = acc[fm][fn];
                #pragma unroll
                for (int r = 0; r < 4; ++r) {
                    int row = rowb + fm * 16 + r;
                    O[(long)row * HDIM + colb + fn * 16] = v[r];
                }
            }
    }
}

// ---------------- combine: out = shared + 2.5 * sum_k w_k * y[slot_k] ----------------
__global__ __launch_bounds__(256) void k_combine(
    float* __restrict__ out, const uint16_t* __restrict__ ybuf,
    const int* __restrict__ slot_of, const float* __restrict__ topk_w)
{
    __shared__ int sl[KTOP];
    __shared__ float sw[KTOP];
    const int t = blockIdx.x, tid = threadIdx.x;
    if (tid < KTOP) {
        sl[tid] = slot_of[t * KTOP + tid];
        sw[tid] = topk_w[t * KTOP + tid] * RSCALE;
    }
    __syncthreads();
    const int h0 = tid << 3;
    float* orow = out + (long)t * HDIM + h0;
    float4 v0 = *(const float4*)(orow);
    float4 v1 = *(const float4*)(orow + 4);
    float a[8] = { v0.x, v0.y, v0.z, v0.w, v1.x, v1.y, v1.z, v1.w };
    #pragma unroll
    for (int k = 0; k < KTOP; ++k) {
        const uint16_t* yr = ybuf + (long)sl[k] * HDIM + h0;
        short8 y = *(const short8*)yr;
        float w = sw[k];
        #pragma unroll
        for (int j = 0; j < 8; ++j)
            a[j] += w * bf2f((uint16_t)y[j]);
    }
    v0.x = a[0]; v0.y = a[1]; v0.z = a[2]; v0.w = a[3];
    v1.x = a[4]; v1.y = a[5]; v1.z = a[6]; v1.w = a[7];
    *(float4*)(orow) = v0;
    *(float4*)(orow + 4) = v1;
}

// ---------------- launch ----------------
extern "C" void kernel_launch(void* const* d_in, const int* in_sizes, int n_in,
                              void* d_out, int out_size, void* d_ws, size_t ws_size,
                              hipStream_t stream)
{
    const float* x  = (const float*)d_in[0];
    const float* gw = (const float*)d_in[1];
    const float* eb = (const float*)d_in[2];
    const float* w1 = (const float*)d_in[3];
    const float* w2 = (const float*)d_in[4];
    const float* s1 = (const float*)d_in[5];
    const float* s2 = (const float*)d_in[6];
    float* out = (float*)d_out;
    char* ws = (char*)d_ws;

    size_t off = 0;
    auto take = [&](size_t b) { size_t r = off; off += (b + 255) & ~(size_t)255; return r; };
    const size_t oXBF = take((size_t)T_TOK * HDIM * 2);
    const size_t oACT = take((size_t)TKTOT * IDIM * 2);
    const size_t oASH = take((size_t)T_TOK * IDIM * 2);
    const size_t oW1T = take((size_t)NEXP * 2048 * 2048 * 2);  // aliased as ybuf after gate_up
    const size_t oW2T = take((size_t)NEXP * 2048 * 1024 * 2);
    const size_t oS1T = take((size_t)2048 * 2048 * 2);
    const size_t oS2T = take((size_t)2048 * 1024 * 2);
    const size_t oTKI = take((size_t)TKTOT * 4);
    const size_t oTKW = take((size_t)TKTOT * 4);
    const size_t oSLT = take((size_t)TKTOT * 4);
    const size_t oPRM = take((size_t)TKTOT * 4);
    const size_t oCNT = take(256);
    const size_t oOFS = take(256);
    const size_t oCUR = take(256);
    const size_t oNT  = take(256);
    const size_t oTE  = take(MAXTILES * 4);
    const size_t oTR  = take(MAXTILES * 4);
    const size_t oTX  = take(MAXTILES * 4);
    (void)ws_size; (void)in_sizes; (void)n_in; (void)out_size;

    uint16_t* xbf  = (uint16_t*)(ws + oXBF);
    uint16_t* act  = (uint16_t*)(ws + oACT);
    uint16_t* ash  = (uint16_t*)(ws + oASH);
    uint16_t* w1t  = (uint16_t*)(ws + oW1T);
    uint16_t* ybuf = (uint16_t*)(ws + oW1T);
    uint16_t* w2t  = (uint16_t*)(ws + oW2T);
    uint16_t* s1t  = (uint16_t*)(ws + oS1T);
    uint16_t* s2t  = (uint16_t*)(ws + oS2T);
    int*   tki  = (int*)(ws + oTKI);
    float* tkw  = (float*)(ws + oTKW);
    int*   slot = (int*)(ws + oSLT);
    int*   prm  = (int*)(ws + oPRM);
    int*   cnt  = (int*)(ws + oCNT);
    int*   ofs  = (int*)(ws + oOFS);
    int*   cur  = (int*)(ws + oCUR);
    int*   nt   = (int*)(ws + oNT);
    int*   te   = (int*)(ws + oTE);
    int*   tr   = (int*)(ws + oTR);
    int*   tx   = (int*)(ws + oTX);

    hipMemsetAsync(ws + oCNT, 0, 256, stream);

    k_router<<<T_TOK / 16, 256, 0, stream>>>(x, gw, eb, tki, tkw, cnt);
    k_scan<<<1, 1, 0, stream>>>(cnt, ofs, cur, te, tr, tx, nt);
    k_scatter<<<TKTOT / 256, 256, 0, stream>>>(tki, cur, prm, slot);

    k_cvt_bf16<<<(T_TOK * HDIM / 4 + 255) / 256, 256, 0, stream>>>(x, xbf, (long)T_TOK * HDIM / 4);
    k_transpose<true ><<<dim3(64, 64, NEXP), 256, 0, stream>>>(w1, w1t, 2048, 2048,
        (long)2048 * 2048, (long)2048 * 2048);
    k_transpose<false><<<dim3(64, 32, NEXP), 256, 0, stream>>>(w2, w2t, 1024, 2048,
        (long)1024 * 2048, (long)2048 * 1024);
    k_transpose<true ><<<dim3(64, 64, 1), 256, 0, stream>>>(s1, s1t, 2048, 2048, 0, 0);
    k_transpose<false><<<dim3(64, 32, 1), 256, 0, stream>>>(s2, s2t, 1024, 2048, 0, 0);

    // shared expert: gate_up (+silu*mul) then down (writes d_out with shared output)
    k_gemm<true, false><<<dim3(T_TOK / 128, 16), 256, 0, stream>>>(
        xbf, s1t, ash, nullptr, te, tr, tx, nt, 2048, 0);
    // routed gate_up (+silu*mul) -> act
    k_gemm<true, true><<<dim3(576, 16), 256, 0, stream>>>(
        xbf, w1t, act, prm, te, tr, tx, nt, 2048, (long)2048 * 2048);
    // shared down -> d_out (f32 store)
    k_gemm<false, false><<<dim3(T_TOK / 128, 16), 256, 0, stream>>>(
        ash, s2t, out, nullptr, te, tr, tx, nt, 1024, 0);
    // routed down -> ybuf (bf16), aliases w1t region (w1t dead by now this call)
    k_gemm<false, true><<<dim3(576, 16), 256, 0, stream>>>(
        act, w2t, ybuf, nullptr, te, tr, tx, nt, 1024, (long)2048 * 1024);

    k_combine<<<T_TOK, 256, 0, stream>>>(out, ybuf, slot, tkw);
}

// Round 2
// 2396.743 us; speedup vs baseline: 1.2727x; 1.2727x over previous
//
#include <hip/hip_runtime.h>
#include <stdint.h>

// ---------------- problem constants ----------------
#define T_TOK 8192
#define HDIM  2048
#define IDIM  1024
#define NEXP  64
#define KTOP  8
#define TGRP  4
#define TKTOT (T_TOK*KTOP)   // 65536
#define MAXTILES 1024
#define RSCALE 2.5f

typedef __attribute__((ext_vector_type(8))) short short8;
typedef __attribute__((ext_vector_type(4))) float f32x4;

__device__ __forceinline__ float bf2f(uint16_t u) {
    union { unsigned i; float f; } v; v.i = ((unsigned)u) << 16; return v.f;
}
__device__ __forceinline__ uint16_t f2bf(float f) {
    union { float f; unsigned i; } v; v.f = f;
    unsigned r = (v.i + 0x7FFFu + ((v.i >> 16) & 1u)) >> 16;
    return (uint16_t)r;
}
__device__ __forceinline__ void gload_lds16(const void* g, void* l) {
    __builtin_amdgcn_global_load_lds(
        (const __attribute__((address_space(1))) void*)g,
        (__attribute__((address_space(3))) void*)l, 16, 0, 0);
}
__device__ __forceinline__ int imin(int a, int b) { return a < b ? a : b; }

// ---------------- router + grouped topk ----------------
__global__ __launch_bounds__(256) void k_router(
    const float* __restrict__ x, const float* __restrict__ gw,
    const float* __restrict__ ebias,
    int* __restrict__ topk_ids, float* __restrict__ topk_w,
    int* __restrict__ counts)
{
    __shared__ float xs[16][132];
    __shared__ float wsb[64][133];
    __shared__ float sc[16][65];
    __shared__ float su[16][65];
    const int tid = threadIdx.x;
    const int e = tid & 63;
    const int tg = tid >> 6;
    const long tblk = (long)blockIdx.x * 16;

    float acc0 = 0.f, acc1 = 0.f, acc2 = 0.f, acc3 = 0.f;
    for (int ch = 0; ch < 16; ++ch) {
        const int h0 = ch << 7;
        for (int i = tid; i < 512; i += 256) {
            int r = i >> 5, c4 = (i & 31) << 2;
            float4 v = *(const float4*)(x + (tblk + r) * HDIM + h0 + c4);
            *(float4*)&xs[r][c4] = v;
        }
        for (int i = tid; i < 8192; i += 256) {
            int r = i >> 7, c = i & 127;
            wsb[r][c] = gw[(long)r * HDIM + h0 + c];
        }
        __syncthreads();
        #pragma unroll 8
        for (int hh = 0; hh < 128; ++hh) {
            float wv = wsb[e][hh];
            acc0 += xs[tg][hh] * wv;
            acc1 += xs[tg + 4][hh] * wv;
            acc2 += xs[tg + 8][hh] * wv;
            acc3 += xs[tg + 12][hh] * wv;
        }
        __syncthreads();
    }
    const float be = ebias[e];
    {
        float s;
        s = 1.f / (1.f + expf(-acc0)); su[tg][e] = s;      sc[tg][e] = s + be;
        s = 1.f / (1.f + expf(-acc1)); su[tg + 4][e] = s;  sc[tg + 4][e] = s + be;
        s = 1.f / (1.f + expf(-acc2)); su[tg + 8][e] = s;  sc[tg + 8][e] = s + be;
        s = 1.f / (1.f + expf(-acc3)); su[tg + 12][e] = s; sc[tg + 12][e] = s + be;
    }
    __syncthreads();
    if (tid < 16) {
        const int t = tid;
        float gs[8];
        #pragma unroll
        for (int g = 0; g < 8; ++g) {
            float m1 = -1e30f, m2 = -1e30f;
            #pragma unroll
            for (int j = 0; j < 8; ++j) {
                float v = sc[t][g * 8 + j];
                if (v > m1) { m2 = m1; m1 = v; } else if (v > m2) { m2 = v; }
            }
            gs[g] = m1 + m2;
        }
        int selmask = 0;
        #pragma unroll
        for (int it = 0; it < TGRP; ++it) {
            float best = -1e30f; int bg = 0;
            #pragma unroll
            for (int g = 0; g < 8; ++g)
                if (!((selmask >> g) & 1) && gs[g] > best) { best = gs[g]; bg = g; }
            selmask |= (1 << bg);
        }
        unsigned long long chosen = 0ull;
        int ids[KTOP]; float wv[KTOP]; float wsum = 0.f;
        #pragma unroll
        for (int it = 0; it < KTOP; ++it) {
            float best = -1e30f; int bi = 0;
            for (int ee = 0; ee < 64; ++ee) {
                if (((selmask >> (ee >> 3)) & 1) && !((chosen >> ee) & 1ull)) {
                    float v = sc[t][ee];
                    if (v > best) { best = v; bi = ee; }
                }
            }
            chosen |= (1ull << bi);
            ids[it] = bi; wv[it] = su[t][bi]; wsum += wv[it];
        }
        const float inv = 1.f / wsum;
        #pragma unroll
        for (int k = 0; k < KTOP; ++k) {
            topk_ids[(tblk + t) * KTOP + k] = ids[k];
            topk_w[(tblk + t) * KTOP + k] = wv[k] * inv;
            atomicAdd(&counts[ids[k]], 1);
        }
    }
}

// ---------------- offsets + tile map (serial, tiny) ----------------
__global__ void k_scan(const int* __restrict__ counts, int* offsets, int* cursor,
                       int* tile_e, int* tile_r0, int* tile_end, int* ntiles)
{
    if (threadIdx.x || blockIdx.x) return;
    int off = 0, nt = 0;
    for (int e = 0; e < NEXP; ++e) {
        offsets[e] = off; cursor[e] = off;
        int c = counts[e];
        for (int m0 = 0; m0 < c; m0 += 128) {
            tile_e[nt] = e; tile_r0[nt] = off + m0; tile_end[nt] = off + c; ++nt;
        }
        off += c;
    }
    *ntiles = nt;
}

__global__ __launch_bounds__(256) void k_scatter(
    const int* __restrict__ topk_ids, int* cursor,
    int* __restrict__ perm_token, int* __restrict__ slot_of)
{
    int i = blockIdx.x * 256 + threadIdx.x;
    if (i >= TKTOT) return;
    int e = topk_ids[i];
    int pos = atomicAdd(&cursor[e], 1);
    perm_token[pos] = i >> 3;
    slot_of[i] = pos;
}

// ---------------- fp32 -> bf16 elementwise ----------------
__global__ __launch_bounds__(256) void k_cvt_bf16(
    const float* __restrict__ in, uint16_t* __restrict__ outp, long n4)
{
    long i = (long)blockIdx.x * 256 + threadIdx.x;
    if (i >= n4) return;
    float4 v = *(const float4*)(in + i * 4);
    uint64_t pk = (uint64_t)f2bf(v.x) | ((uint64_t)f2bf(v.y) << 16)
                | ((uint64_t)f2bf(v.z) << 32) | ((uint64_t)f2bf(v.w) << 48);
    *(uint64_t*)(outp + i * 4) = pk;
}

// ---------------- tiled transpose + cvt: src f32 [R][C] -> dst bf16 [C'][R] ----------------
// INTER: gate/up row interleave c -> 2*(c&1023) + (c>>10)
// 64x64 tiles, 256 threads. float4 coalesced reads; short8 coalesced writes.
template<bool INTER>
__global__ __launch_bounds__(256) void k_transpose2(
    const float* __restrict__ src, uint16_t* __restrict__ dst,
    int R, int C, long sStride, long dStride)
{
    __shared__ float tile[64][65];
    const int c0 = blockIdx.x << 6, r0 = blockIdx.y << 6, s = blockIdx.z;
    const float* S = src + (long)s * sStride;
    uint16_t* D = dst + (long)s * dStride;
    const int lc = (threadIdx.x & 15) << 2;
    const int lr = threadIdx.x >> 4;
    #pragma unroll
    for (int p = 0; p < 4; ++p) {
        int y = lr + p * 16;
        float4 v = *(const float4*)(S + (long)(r0 + y) * C + c0 + lc);
        tile[y][lc] = v.x; tile[y][lc + 1] = v.y;
        tile[y][lc + 2] = v.z; tile[y][lc + 3] = v.w;
    }
    __syncthreads();
    const int wc = threadIdx.x >> 3;          // 0..31: out-row within pass
    const int wx = (threadIdx.x & 7) << 3;    // 0..56: 8-elem chunk
    #pragma unroll
    for (int p = 0; p < 2; ++p) {
        int c = wc + p * 32;                  // local out row (= source col)
        short8 v;
        #pragma unroll
        for (int j = 0; j < 8; ++j) v[j] = (short)f2bf(tile[wx + j][c]);
        int cg = c0 + c;
        int rd = INTER ? (((cg & (IDIM - 1)) << 1) + (cg >> 10)) : cg;
        *(short8*)(D + (long)rd * R + r0 + wx) = v;
    }
}

// ---------------- MFMA GEMM v2 ----------------
// 128x128 tile, BK=64, 4 waves, 16x16x32 bf16, XOR-swizzled LDS (conflict-free),
// persistent dynamic-queue blocks for ROUTED (B-panel L2/L3 reuse).
template<bool GATEUP, bool ROUTED>
__global__ __launch_bounds__(256) void k_gemm2(
    const uint16_t* __restrict__ A, const uint16_t* __restrict__ Bw,
    void* __restrict__ OutP,
    const int* __restrict__ perm_token,
    const int* __restrict__ tile_e, const int* __restrict__ tile_r0,
    const int* __restrict__ tile_end, const int* __restrict__ ntiles,
    int* __restrict__ qcur,
    int Kd, long expStride)
{
    __shared__ uint16_t lds[2 * 128 * 64];   // A: bytes [0,16384), B: [16384,32768)
    const int tid = threadIdx.x, lane = tid & 63, wid = tid >> 6;

    // staging geometry: 4 instrs/region/wave; LDS byte o = wid*4096 + j*1024 + lane*16
    int aRow[4], aSlotB[4];
    #pragma unroll
    for (int j = 0; j < 4; ++j) {
        int o = wid * 4096 + j * 1024 + lane * 16;
        int r = o >> 7;                        // 128B rows
        aRow[j] = r;
        aSlotB[j] = ((((o >> 4) & 7) ^ (r & 7)) << 4); // pre-swizzled source slot (bytes)
    }

    // fragment geometry
    const int wm = wid >> 1, wn = wid & 1;
    const int rA = wm * 64 + (lane & 15);
    const int rB = wn * 64 + (lane & 15);
    const int kc = lane >> 4;                  // 0..3
    const int swz = lane & 7;                  // = row&7 for frag rows
    const int es0 = ((kc) ^ swz) << 4;         // kk=0 slot byte offset
    const int es1 = ((4 + kc) ^ swz) << 4;     // kk=1
    char* const ldsb = (char*)lds;
    const int nK = Kd >> 6;

    const int ntl = ROUTED ? ntiles[0] : 0;
    const int nitems = ntl << 4;
    __shared__ int s_item;

    for (;;) {
        int row0, end, n0; const uint16_t* Bbase;
        if (ROUTED) {
            __syncthreads();
            if (tid == 0) s_item = atomicAdd(qcur, 1);
            __syncthreads();
            const int it = s_item;
            if (it >= nitems) break;
            const int tIdx = it >> 4;          // tile-major: 16 n-panels of a tile adjacent
            n0 = (it & 15) << 7;
            row0 = tile_r0[tIdx]; end = tile_end[tIdx];
            Bbase = Bw + (long)tile_e[tIdx] * expStride;
        } else {
            row0 = (blockIdx.x >> 4) << 7; end = row0 + 128;
            n0 = (blockIdx.x & 15) << 7;
            Bbase = Bw;
        }

        // source pointers (elements)
        const uint16_t* pa[4]; const uint16_t* pb[4];
        #pragma unroll
        for (int j = 0; j < 4; ++j) {
            int s = row0 + aRow[j];
            if (ROUTED) s = imin(s, end - 1);
            long grow = (GATEUP && ROUTED) ? (long)perm_token[s] : (long)s;
            pa[j] = A + grow * Kd + (aSlotB[j] >> 1);
            pb[j] = Bbase + (long)(n0 + aRow[j]) * Kd + (aSlotB[j] >> 1);
        }

        f32x4 acc[4][4];
        #pragma unroll
        for (int i = 0; i < 4; ++i)
            #pragma unroll
            for (int j = 0; j < 4; ++j) {
                f32x4 z = {0.f, 0.f, 0.f, 0.f};
                acc[i][j] = z;
            }

        for (int kt = 0; kt < nK; ++kt) {
            #pragma unroll
            for (int j = 0; j < 4; ++j)
                gload_lds16(pa[j], ldsb + wid * 4096 + j * 1024);
            #pragma unroll
            for (int j = 0; j < 4; ++j)
                gload_lds16(pb[j], ldsb + 16384 + wid * 4096 + j * 1024);
            #pragma unroll
            for (int j = 0; j < 4; ++j) { pa[j] += 64; pb[j] += 64; }
            __syncthreads();   // vmcnt drained by compiler before barrier
            short8 af[4], bfr[4];
            // kk = 0
            #pragma unroll
            for (int f = 0; f < 4; ++f)
                af[f] = *(const short8*)(ldsb + (rA + f * 16) * 128 + es0);
            #pragma unroll
            for (int f = 0; f < 4; ++f)
                bfr[f] = *(const short8*)(ldsb + 16384 + (rB + f * 16) * 128 + es0);
            #pragma unroll
            for (int fm = 0; fm < 4; ++fm)
                #pragma unroll
                for (int fn = 0; fn < 4; ++fn)
                    acc[fm][fn] = __builtin_amdgcn_mfma_f32_16x16x32_bf16(
                        af[fm], bfr[fn], acc[fm][fn], 0, 0, 0);
            // kk = 1
            #pragma unroll
            for (int f = 0; f < 4; ++f)
                af[f] = *(const short8*)(ldsb + (rA + f * 16) * 128 + es1);
            #pragma unroll
            for (int f = 0; f < 4; ++f)
                bfr[f] = *(const short8*)(ldsb + 16384 + (rB + f * 16) * 128 + es1);
            #pragma unroll
            for (int fm = 0; fm < 4; ++fm)
                #pragma unroll
                for (int fn = 0; fn < 4; ++fn)
                    acc[fm][fn] = __builtin_amdgcn_mfma_f32_16x16x32_bf16(
                        af[fm], bfr[fn], acc[fm][fn], 0, 0, 0);
            __syncthreads();   // protect LDS before next stage
        }

        // epilogue
        const int colb = n0 + wn * 64 + (lane & 15);
        const int rowb = row0 + wm * 64 + (kc << 2);
        if (GATEUP) {
            uint16_t* Oact = (uint16_t*)OutP;
            const bool evenl = ((lane & 1) == 0);
            #pragma unroll
            for (int fm = 0; fm < 4; ++fm)
                #pragma unroll
                for (int fn = 0; fn < 4; ++fn) {
                    f32x4 v = acc[fm][fn];
                    #pragma unroll
                    for (int r = 0; r < 4; ++r) {
                        float g = v[r];
                        float u = __shfl_xor(g, 1, 64);
                        int row = rowb + fm * 16 + r;
                        if (evenl && (!ROUTED || row < end)) {
                            int j = (colb + fn * 16) >> 1;
                            float sg = g / (1.f + expf(-g));
                            Oact[(long)row * IDIM + j] = f2bf(sg * u);
                        }
                    }
                }
        } else if (ROUTED) {
            uint16_t* Y = (uint16_t*)OutP;
            #pragma unroll
            for (int fm = 0; fm < 4; ++fm)
                #pragma unroll
                for (int fn = 0; fn < 4; ++fn) {
                    f32x4 v = acc[fm][fn];
                    #pragma unroll
                    for (int r = 0; r < 4; ++r) {
                        int row = rowb + fm * 16 + r;
                        if (row < end)
                            Y[(long)row * HDIM + colb + fn * 16] = f2bf(v[r]);
                    }
                }
        } else {
            float* O = (float*)OutP;
            #pragma unroll
            for (int fm = 0; fm < 4; ++fm)
                #pragma unroll
                for (int fn = 0; fn < 4; ++fn) {
                    f32x4 v = acc[fm][fn];
                    #pragma unroll
                    for (int r = 0; r < 4; ++r) {
                        int row = rowb + fm * 16 + r;
                        O[(long)row * HDIM + colb + fn * 16] = v[r];
                    }
                }
        }
        if (!ROUTED) break;
    }
}

// ---------------- combine: out = shared + 2.5 * sum_k w_k * y[slot_k] ----------------
__global__ __launch_bounds__(256) void k_combine(
    float* __restrict__ out, const uint16_t* __restrict__ ybuf,
    const int* __restrict__ slot_of, const float* __restrict__ topk_w)
{
    __shared__ int sl[KTOP];
    __shared__ float sw[KTOP];
    const int t = blockIdx.x, tid = threadIdx.x;
    if (tid < KTOP) {
        sl[tid] = slot_of[t * KTOP + tid];
        sw[tid] = topk_w[t * KTOP + tid] * RSCALE;
    }
    __syncthreads();
    const int h0 = tid << 3;
    float* orow = out + (long)t * HDIM + h0;
    float4 v0 = *(const float4*)(orow);
    float4 v1 = *(const float4*)(orow + 4);
    float a[8] = { v0.x, v0.y, v0.z, v0.w, v1.x, v1.y, v1.z, v1.w };
    #pragma unroll
    for (int k = 0; k < KTOP; ++k) {
        const uint16_t* yr = ybuf + (long)sl[k] * HDIM + h0;
        short8 y = *(const short8*)yr;
        float w = sw[k];
        #pragma unroll
        for (int j = 0; j < 8; ++j)
            a[j] += w * bf2f((uint16_t)y[j]);
    }
    v0.x = a[0]; v0.y = a[1]; v0.z = a[2]; v0.w = a[3];
    v1.x = a[4]; v1.y = a[5]; v1.z = a[6]; v1.w = a[7];
    *(float4*)(orow) = v0;
    *(float4*)(orow + 4) = v1;
}

// ---------------- launch ----------------
extern "C" void kernel_launch(void* const* d_in, const int* in_sizes, int n_in,
                              void* d_out, int out_size, void* d_ws, size_t ws_size,
                              hipStream_t stream)
{
    const float* x  = (const float*)d_in[0];
    const float* gw = (const float*)d_in[1];
    const float* eb = (const float*)d_in[2];
    const float* w1 = (const float*)d_in[3];
    const float* w2 = (const float*)d_in[4];
    const float* s1 = (const float*)d_in[5];
    const float* s2 = (const float*)d_in[6];
    float* out = (float*)d_out;
    char* ws = (char*)d_ws;

    size_t off = 0;
    auto take = [&](size_t b) { size_t r = off; off += (b + 255) & ~(size_t)255; return r; };
    const size_t oXBF = take((size_t)T_TOK * HDIM * 2);
    const size_t oACT = take((size_t)TKTOT * IDIM * 2);
    const size_t oASH = take((size_t)T_TOK * IDIM * 2);
    const size_t oW1T = take((size_t)NEXP * 2048 * 2048 * 2);  // aliased as ybuf after gate_up
    const size_t oW2T = take((size_t)NEXP * 2048 * 1024 * 2);
    const size_t oS1T = take((size_t)2048 * 2048 * 2);
    const size_t oS2T = take((size_t)2048 * 1024 * 2);
    const size_t oTKI = take((size_t)TKTOT * 4);
    const size_t oTKW = take((size_t)TKTOT * 4);
    const size_t oSLT = take((size_t)TKTOT * 4);
    const size_t oPRM = take((size_t)TKTOT * 4);
    const size_t oCTL = take(1024);     // [0..63]=counts, [64]=q0, [65]=q1
    const size_t oOFS = take(256);
    const size_t oCUR = take(256);
    const size_t oNT  = take(256);
    const size_t oTE  = take(MAXTILES * 4);
    const size_t oTR  = take(MAXTILES * 4);
    const size_t oTX  = take(MAXTILES * 4);
    (void)ws_size; (void)in_sizes; (void)n_in; (void)out_size;

    uint16_t* xbf  = (uint16_t*)(ws + oXBF);
    uint16_t* act  = (uint16_t*)(ws + oACT);
    uint16_t* ash  = (uint16_t*)(ws + oASH);
    uint16_t* w1t  = (uint16_t*)(ws + oW1T);
    uint16_t* ybuf = (uint16_t*)(ws + oW1T);
    uint16_t* w2t  = (uint16_t*)(ws + oW2T);
    uint16_t* s1t  = (uint16_t*)(ws + oS1T);
    uint16_t* s2t  = (uint16_t*)(ws + oS2T);
    int*   tki  = (int*)(ws + oTKI);
    float* tkw  = (float*)(ws + oTKW);
    int*   slot = (int*)(ws + oSLT);
    int*   prm  = (int*)(ws + oPRM);
    int*   ctl  = (int*)(ws + oCTL);
    int*   ofs  = (int*)(ws + oOFS);
    int*   cur  = (int*)(ws + oCUR);
    int*   nt   = (int*)(ws + oNT);
    int*   te   = (int*)(ws + oTE);
    int*   tr   = (int*)(ws + oTR);
    int*   tx   = (int*)(ws + oTX);

    hipMemsetAsync(ws + oCTL, 0, 1024, stream);

    k_router<<<T_TOK / 16, 256, 0, stream>>>(x, gw, eb, tki, tkw, ctl);
    k_scan<<<1, 1, 0, stream>>>(ctl, ofs, cur, te, tr, tx, nt);
    k_scatter<<<TKTOT / 256, 256, 0, stream>>>(tki, cur, prm, slot);

    k_cvt_bf16<<<(T_TOK * HDIM / 4 + 255) / 256, 256, 0, stream>>>(x, xbf, (long)T_TOK * HDIM / 4);
    k_transpose2<true ><<<dim3(32, 32, NEXP), 256, 0, stream>>>(w1, w1t, 2048, 2048,
        (long)2048 * 2048, (long)2048 * 2048);
    k_transpose2<false><<<dim3(32, 16, NEXP), 256, 0, stream>>>(w2, w2t, 1024, 2048,
        (long)1024 * 2048, (long)2048 * 1024);
    k_transpose2<true ><<<dim3(32, 32, 1), 256, 0, stream>>>(s1, s1t, 2048, 2048, 0, 0);
    k_transpose2<false><<<dim3(32, 16, 1), 256, 0, stream>>>(s2, s2t, 1024, 2048, 0, 0);

    // shared expert gate_up (+silu*mul) -> ash
    k_gemm2<true, false><<<dim3((T_TOK / 128) * 16), 256, 0, stream>>>(
        xbf, s1t, ash, nullptr, te, tr, tx, nt, nullptr, 2048, 0);
    // routed gate_up (+silu*mul) -> act   (persistent, queue q0 = ctl[64])
    k_gemm2<true, true><<<dim3(768), 256, 0, stream>>>(
        xbf, w1t, act, prm, te, tr, tx, nt, ctl + 64, 2048, (long)2048 * 2048);
    // shared down -> d_out (f32)
    k_gemm2<false, false><<<dim3((T_TOK / 128) * 16), 256, 0, stream>>>(
        ash, s2t, out, nullptr, te, tr, tx, nt, nullptr, 1024, 0);
    // routed down -> ybuf (bf16, aliases w1t; queue q1 = ctl[65])
    k_gemm2<false, true><<<dim3(768), 256, 0, stream>>>(
        act, w2t, ybuf, nullptr, te, tr, tx, nt, ctl + 65, 1024, (long)2048 * 1024);

    k_combine<<<T_TOK, 256, 0, stream>>>(out, ybuf, slot, tkw);
}

// Round 3
// 2313.739 us; speedup vs baseline: 1.3183x; 1.0359x over previous
//
#include <hip/hip_runtime.h>
#include <stdint.h>

// ---------------- problem constants ----------------
#define T_TOK 8192
#define HDIM  2048
#define IDIM  1024
#define NEXP  64
#define KTOP  8
#define TGRP  4
#define TKTOT (T_TOK*KTOP)   // 65536
#define MAXITEMS 4096
#define RSCALE 2.5f

typedef __attribute__((ext_vector_type(8))) short short8;
typedef __attribute__((ext_vector_type(4))) float f32x4;

__device__ __forceinline__ float bf2f(uint16_t u) {
    union { unsigned i; float f; } v; v.i = ((unsigned)u) << 16; return v.f;
}
__device__ __forceinline__ uint16_t f2bf(float f) {
    union { float f; unsigned i; } v; v.f = f;
    unsigned r = (v.i + 0x7FFFu + ((v.i >> 16) & 1u)) >> 16;
    return (uint16_t)r;
}
__device__ __forceinline__ void gload_lds16(const void* g, void* l) {
    __builtin_amdgcn_global_load_lds(
        (const __attribute__((address_space(1))) void*)g,
        (__attribute__((address_space(3))) void*)l, 16, 0, 0);
}
__device__ __forceinline__ int imin(int a, int b) { return a < b ? a : b; }

// ---------------- router + grouped topk (unchanged, verified) ----------------
__global__ __launch_bounds__(256) void k_router(
    const float* __restrict__ x, const float* __restrict__ gw,
    const float* __restrict__ ebias,
    int* __restrict__ topk_ids, float* __restrict__ topk_w,
    int* __restrict__ counts)
{
    __shared__ float xs[16][132];
    __shared__ float wsb[64][133];
    __shared__ float sc[16][65];
    __shared__ float su[16][65];
    const int tid = threadIdx.x;
    const int e = tid & 63;
    const int tg = tid >> 6;
    const long tblk = (long)blockIdx.x * 16;

    float acc0 = 0.f, acc1 = 0.f, acc2 = 0.f, acc3 = 0.f;
    for (int ch = 0; ch < 16; ++ch) {
        const int h0 = ch << 7;
        for (int i = tid; i < 512; i += 256) {
            int r = i >> 5, c4 = (i & 31) << 2;
            float4 v = *(const float4*)(x + (tblk + r) * HDIM + h0 + c4);
            *(float4*)&xs[r][c4] = v;
        }
        for (int i = tid; i < 8192; i += 256) {
            int r = i >> 7, c = i & 127;
            wsb[r][c] = gw[(long)r * HDIM + h0 + c];
        }
        __syncthreads();
        #pragma unroll 8
        for (int hh = 0; hh < 128; ++hh) {
            float wv = wsb[e][hh];
            acc0 += xs[tg][hh] * wv;
            acc1 += xs[tg + 4][hh] * wv;
            acc2 += xs[tg + 8][hh] * wv;
            acc3 += xs[tg + 12][hh] * wv;
        }
        __syncthreads();
    }
    const float be = ebias[e];
    {
        float s;
        s = 1.f / (1.f + expf(-acc0)); su[tg][e] = s;      sc[tg][e] = s + be;
        s = 1.f / (1.f + expf(-acc1)); su[tg + 4][e] = s;  sc[tg + 4][e] = s + be;
        s = 1.f / (1.f + expf(-acc2)); su[tg + 8][e] = s;  sc[tg + 8][e] = s + be;
        s = 1.f / (1.f + expf(-acc3)); su[tg + 12][e] = s; sc[tg + 12][e] = s + be;
    }
    __syncthreads();
    if (tid < 16) {
        const int t = tid;
        float gs[8];
        #pragma unroll
        for (int g = 0; g < 8; ++g) {
            float m1 = -1e30f, m2 = -1e30f;
            #pragma unroll
            for (int j = 0; j < 8; ++j) {
                float v = sc[t][g * 8 + j];
                if (v > m1) { m2 = m1; m1 = v; } else if (v > m2) { m2 = v; }
            }
            gs[g] = m1 + m2;
        }
        int selmask = 0;
        #pragma unroll
        for (int it = 0; it < TGRP; ++it) {
            float best = -1e30f; int bg = 0;
            #pragma unroll
            for (int g = 0; g < 8; ++g)
                if (!((selmask >> g) & 1) && gs[g] > best) { best = gs[g]; bg = g; }
            selmask |= (1 << bg);
        }
        unsigned long long chosen = 0ull;
        int ids[KTOP]; float wv[KTOP]; float wsum = 0.f;
        #pragma unroll
        for (int it = 0; it < KTOP; ++it) {
            float best = -1e30f; int bi = 0;
            for (int ee = 0; ee < 64; ++ee) {
                if (((selmask >> (ee >> 3)) & 1) && !((chosen >> ee) & 1ull)) {
                    float v = sc[t][ee];
                    if (v > best) { best = v; bi = ee; }
                }
            }
            chosen |= (1ull << bi);
            ids[it] = bi; wv[it] = su[t][bi]; wsum += wv[it];
        }
        const float inv = 1.f / wsum;
        #pragma unroll
        for (int k = 0; k < KTOP; ++k) {
            topk_ids[(tblk + t) * KTOP + k] = ids[k];
            topk_w[(tblk + t) * KTOP + k] = wv[k] * inv;
            atomicAdd(&counts[ids[k]], 1);
        }
    }
}

// ---------------- offsets + item list (1 wave) ----------------
// items ordered: expert-major, n-panel, M-tile(256)  -> B panel L2 reuse
__global__ __launch_bounds__(64) void k_scan2(
    const int* __restrict__ counts, int* offsets, int* cursor,
    int* __restrict__ it_r0, int* __restrict__ it_end,
    int* __restrict__ it_e, int* __restrict__ it_n0, int* __restrict__ nitems)
{
    const int e = threadIdx.x;           // 0..63, one wave
    const int c = counts[e];
    int pre = c;
    #pragma unroll
    for (int d = 1; d < 64; d <<= 1) {
        int v = __shfl_up(pre, d, 64);
        if (e >= d) pre += v;
    }
    const int offE = pre - c;
    offsets[e] = offE; cursor[e] = offE;
    const int ntl = (c + 255) >> 8;
    int ipre = ntl;
    #pragma unroll
    for (int d = 1; d < 64; d <<= 1) {
        int v = __shfl_up(ipre, d, 64);
        if (e >= d) ipre += v;
    }
    const int ibase = (ipre - ntl) * 8;
    for (int p = 0; p < 8; ++p)
        for (int t = 0; t < ntl; ++t) {
            int idx = ibase + p * ntl + t;
            it_r0[idx] = offE + t * 256;
            it_end[idx] = offE + c;
            it_e[idx] = e;
            it_n0[idx] = p << 8;
        }
    if (e == 63) *nitems = ibase + ntl * 8;
}

__global__ __launch_bounds__(256) void k_scatter(
    const int* __restrict__ topk_ids, int* cursor,
    int* __restrict__ perm_token, int* __restrict__ slot_of)
{
    int i = blockIdx.x * 256 + threadIdx.x;
    if (i >= TKTOT) return;
    int e = topk_ids[i];
    int pos = atomicAdd(&cursor[e], 1);
    perm_token[pos] = i >> 3;
    slot_of[i] = pos;
}

// ---------------- fp32 -> bf16 elementwise ----------------
__global__ __launch_bounds__(256) void k_cvt_bf16(
    const float* __restrict__ in, uint16_t* __restrict__ outp, long n4)
{
    long i = (long)blockIdx.x * 256 + threadIdx.x;
    if (i >= n4) return;
    float4 v = *(const float4*)(in + i * 4);
    uint64_t pk = (uint64_t)f2bf(v.x) | ((uint64_t)f2bf(v.y) << 16)
                | ((uint64_t)f2bf(v.z) << 32) | ((uint64_t)f2bf(v.w) << 48);
    *(uint64_t*)(outp + i * 4) = pk;
}

// ---------------- tiled transpose + cvt (unchanged) ----------------
template<bool INTER>
__global__ __launch_bounds__(256) void k_transpose2(
    const float* __restrict__ src, uint16_t* __restrict__ dst,
    int R, int C, long sStride, long dStride)
{
    __shared__ float tile[64][65];
    const int c0 = blockIdx.x << 6, r0 = blockIdx.y << 6, s = blockIdx.z;
    const float* S = src + (long)s * sStride;
    uint16_t* D = dst + (long)s * dStride;
    const int lc = (threadIdx.x & 15) << 2;
    const int lr = threadIdx.x >> 4;
    #pragma unroll
    for (int p = 0; p < 4; ++p) {
        int y = lr + p * 16;
        float4 v = *(const float4*)(S + (long)(r0 + y) * C + c0 + lc);
        tile[y][lc] = v.x; tile[y][lc + 1] = v.y;
        tile[y][lc + 2] = v.z; tile[y][lc + 3] = v.w;
    }
    __syncthreads();
    const int wc = threadIdx.x >> 3;
    const int wx = (threadIdx.x & 7) << 3;
    #pragma unroll
    for (int p = 0; p < 2; ++p) {
        int c = wc + p * 32;
        short8 v;
        #pragma unroll
        for (int j = 0; j < 8; ++j) v[j] = (short)f2bf(tile[wx + j][c]);
        int cg = c0 + c;
        int rd = INTER ? (((cg & (IDIM - 1)) << 1) + (cg >> 10)) : cg;
        *(short8*)(D + (long)rd * R + r0 + wx) = v;
    }
}

// ---------------- MFMA GEMM v3: 256x256, 8 waves, 4-buffer counted-vmcnt pipeline ----
// K processed in 32-wide sub-tiles. LDS: 4 bufs x (A 16KB + B 16KB) = 128KB.
// Pipeline depth 3: stage j+3 while computing j; s_waitcnt vmcnt(8) (= subtiles
// j+1,j+2 in flight) before the per-subtile barrier. setprio around MFMA cluster.
// Conflict-free XOR swizzle: slot' = slot ^ ((row>>1)&3) (64B rows, 4x16B slots).
template<bool GATEUP, bool ROUTED>
__global__ __launch_bounds__(512, 2) void k_gemm3(
    const uint16_t* __restrict__ A, const uint16_t* __restrict__ Bw,
    void* __restrict__ OutP,
    const int* __restrict__ perm_token,
    const int* __restrict__ it_r0, const int* __restrict__ it_end,
    const int* __restrict__ it_e, const int* __restrict__ it_n0,
    const int* __restrict__ nitems, int* __restrict__ qcur,
    int Kd, long expStride)
{
    __shared__ char ldsb[4 * 32768];
    __shared__ int s_item;
    const int tid = threadIdx.x, lane = tid & 63, wid = tid >> 6;
    const int wm = wid >> 2, wn = wid & 3;          // 2M x 4N wave grid

    // staging geometry: per wave 2 chunks of A + 2 of B; chunk = 16 rows x 64B
    const int rchunk = lane >> 2;                                   // 0..15
    const int swzS = ((lane & 3) ^ ((lane >> 3) & 3)) << 3;         // src k-elem off
    // fragment read offsets (bytes within A/B region of a buffer)
    const int swzR = ((lane >> 4) ^ ((lane >> 1) & 3)) << 4;
    const int aoff = (wm * 128 + (lane & 15)) * 64 + swzR;
    const int boff = (wn * 64 + (lane & 15)) * 64 + swzR;
    const int ldst0 = (wid * 2) * 1024;
    const int ldst1 = (wid * 2 + 1) * 1024;

    const int nSub = Kd >> 5;
    const int NI = ROUTED ? nitems[0] : 0;

    for (;;) {
        int row0, end, n0; long eoff;
        if (ROUTED) {
            __syncthreads();                  // also fences LDS reuse across items
            if (tid == 0) s_item = atomicAdd(qcur, 1);
            __syncthreads();
            const int it = s_item;
            if (it >= NI) break;
            row0 = it_r0[it]; end = it_end[it]; n0 = it_n0[it];
            eoff = (long)it_e[it] * expStride;
        } else {
            row0 = (int)(blockIdx.x >> 3) << 8;
            end = row0 + 256;
            n0 = (int)(blockIdx.x & 7) << 8;
            eoff = 0;
        }

        const uint16_t *pA0, *pA1, *pB0, *pB1;
        {
            int r0l = (wid * 2) * 16 + rchunk;
            int r1l = (wid * 2 + 1) * 16 + rchunk;
            int ra0 = row0 + r0l, ra1 = row0 + r1l;
            if (ROUTED) { ra0 = imin(ra0, end - 1); ra1 = imin(ra1, end - 1); }
            long ga0 = (GATEUP && ROUTED) ? (long)perm_token[ra0] : (long)ra0;
            long ga1 = (GATEUP && ROUTED) ? (long)perm_token[ra1] : (long)ra1;
            pA0 = A + ga0 * Kd + swzS;
            pA1 = A + ga1 * Kd + swzS;
            pB0 = Bw + eoff + (long)(n0 + r0l) * Kd + swzS;
            pB1 = Bw + eoff + (long)(n0 + r1l) * Kd + swzS;
        }

        f32x4 acc[8][4];
        #pragma unroll
        for (int f = 0; f < 8; ++f)
            #pragma unroll
            for (int g = 0; g < 4; ++g) { f32x4 z = {0.f,0.f,0.f,0.f}; acc[f][g] = z; }

        // prologue: stage sub-tiles 0,1,2
        #pragma unroll
        for (int j = 0; j < 3; ++j) {
            char* bb = ldsb + j * 32768;
            gload_lds16(pA0 + (j << 5), bb + ldst0);
            gload_lds16(pA1 + (j << 5), bb + ldst1);
            gload_lds16(pB0 + (j << 5), bb + 16384 + ldst0);
            gload_lds16(pB1 + (j << 5), bb + 16384 + ldst1);
        }

        for (int j = 0; j < nSub; ++j) {
            asm volatile("s_waitcnt vmcnt(8)" ::: "memory");  // sub-tile j landed
            __builtin_amdgcn_s_barrier();
            if (j + 3 < nSub) {                 // stage j+3 into buf (j+3)&3 (= (j-1)&3, reads done)
                const int js = j + 3;
                char* bb = ldsb + (js & 3) * 32768;
                gload_lds16(pA0 + (js << 5), bb + ldst0);
                gload_lds16(pA1 + (js << 5), bb + ldst1);
                gload_lds16(pB0 + (js << 5), bb + 16384 + ldst0);
                gload_lds16(pB1 + (js << 5), bb + 16384 + ldst1);
            }
            const char* bb = ldsb + (j & 3) * 32768;
            short8 av[8], bv[4];
            #pragma unroll
            for (int f = 0; f < 8; ++f)
                av[f] = *(const short8*)(bb + aoff + f * 1024);
            #pragma unroll
            for (int g = 0; g < 4; ++g)
                bv[g] = *(const short8*)(bb + 16384 + boff + g * 1024);
            __builtin_amdgcn_s_setprio(1);
            #pragma unroll
            for (int f = 0; f < 8; ++f)
                #pragma unroll
                for (int g = 0; g < 4; ++g)
                    acc[f][g] = __builtin_amdgcn_mfma_f32_16x16x32_bf16(
                        av[f], bv[g], acc[f][g], 0, 0, 0);
            __builtin_amdgcn_s_setprio(0);
        }

        // epilogue
        const int colb = n0 + wn * 64 + (lane & 15);
        const int rowbase = row0 + wm * 128 + ((lane >> 4) << 2);
        if (GATEUP) {
            uint16_t* Oact = (uint16_t*)OutP;
            const bool evenl = ((lane & 1) == 0);
            #pragma unroll
            for (int f = 0; f < 8; ++f)
                #pragma unroll
                for (int g = 0; g < 4; ++g) {
                    f32x4 v = acc[f][g];
                    #pragma unroll
                    for (int r = 0; r < 4; ++r) {
                        float gg = v[r];
                        float uu = __shfl_xor(gg, 1, 64);
                        int row = rowbase + f * 16 + r;
                        if (evenl && (!ROUTED || row < end)) {
                            int jcol = (colb + g * 16) >> 1;
                            float sg = gg / (1.f + __expf(-gg));
                            Oact[(long)row * IDIM + jcol] = f2bf(sg * uu);
                        }
                    }
                }
        } else if (ROUTED) {
            uint16_t* Y = (uint16_t*)OutP;
            #pragma unroll
            for (int f = 0; f < 8; ++f)
                #pragma unroll
                for (int g = 0; g < 4; ++g) {
                    f32x4 v = acc[f][g];
                    #pragma unroll
                    for (int r = 0; r < 4; ++r) {
                        int row = rowbase + f * 16 + r;
                        if (row < end)
                            Y[(long)row * HDIM + colb + g * 16] = f2bf(v[r]);
                    }
                }
        } else {
            float* O = (float*)OutP;
            #pragma unroll
            for (int f = 0; f < 8; ++f)
                #pragma unroll
                for (int g = 0; g < 4; ++g) {
                    f32x4 v = acc[f][g];
                    #pragma unroll
                    for (int r = 0; r < 4; ++r) {
                        int row = rowbase + f * 16 + r;
                        O[(long)row * HDIM + colb + g * 16] = v[r];
                    }
                }
        }
        if (!ROUTED) break;
    }
}

// ---------------- combine: out = shared + 2.5 * sum_k w_k * y[slot_k] ----------------
__global__ __launch_bounds__(256) void k_combine(
    float* __restrict__ out, const uint16_t* __restrict__ ybuf,
    const int* __restrict__ slot_of, const float* __restrict__ topk_w)
{
    __shared__ int sl[KTOP];
    __shared__ float sw[KTOP];
    const int t = blockIdx.x, tid = threadIdx.x;
    if (tid < KTOP) {
        sl[tid] = slot_of[t * KTOP + tid];
        sw[tid] = topk_w[t * KTOP + tid] * RSCALE;
    }
    __syncthreads();
    const int h0 = tid << 3;
    float* orow = out + (long)t * HDIM + h0;
    float4 v0 = *(const float4*)(orow);
    float4 v1 = *(const float4*)(orow + 4);
    float a[8] = { v0.x, v0.y, v0.z, v0.w, v1.x, v1.y, v1.z, v1.w };
    #pragma unroll
    for (int k = 0; k < KTOP; ++k) {
        const uint16_t* yr = ybuf + (long)sl[k] * HDIM + h0;
        short8 y = *(const short8*)yr;
        float w = sw[k];
        #pragma unroll
        for (int j = 0; j < 8; ++j)
            a[j] += w * bf2f((uint16_t)y[j]);
    }
    v0.x = a[0]; v0.y = a[1]; v0.z = a[2]; v0.w = a[3];
    v1.x = a[4]; v1.y = a[5]; v1.z = a[6]; v1.w = a[7];
    *(float4*)(orow) = v0;
    *(float4*)(orow + 4) = v1;
}

// ---------------- launch ----------------
extern "C" void kernel_launch(void* const* d_in, const int* in_sizes, int n_in,
                              void* d_out, int out_size, void* d_ws, size_t ws_size,
                              hipStream_t stream)
{
    const float* x  = (const float*)d_in[0];
    const float* gw = (const float*)d_in[1];
    const float* eb = (const float*)d_in[2];
    const float* w1 = (const float*)d_in[3];
    const float* w2 = (const float*)d_in[4];
    const float* s1 = (const float*)d_in[5];
    const float* s2 = (const float*)d_in[6];
    float* out = (float*)d_out;
    char* ws = (char*)d_ws;

    size_t off = 0;
    auto take = [&](size_t b) { size_t r = off; off += (b + 255) & ~(size_t)255; return r; };
    const size_t oXBF = take((size_t)T_TOK * HDIM * 2);
    const size_t oACT = take((size_t)TKTOT * IDIM * 2);
    const size_t oASH = take((size_t)T_TOK * IDIM * 2);
    const size_t oW1T = take((size_t)NEXP * 2048 * 2048 * 2);  // aliased as ybuf after gate_up
    const size_t oW2T = take((size_t)NEXP * 2048 * 1024 * 2);
    const size_t oS1T = take((size_t)2048 * 2048 * 2);
    const size_t oS2T = take((size_t)2048 * 1024 * 2);
    const size_t oTKI = take((size_t)TKTOT * 4);
    const size_t oTKW = take((size_t)TKTOT * 4);
    const size_t oSLT = take((size_t)TKTOT * 4);
    const size_t oPRM = take((size_t)TKTOT * 4);
    const size_t oCTL = take(1024);     // [0..63]=counts, [64]=q0, [65]=q1
    const size_t oOFS = take(256);
    const size_t oCUR = take(256);
    const size_t oNT  = take(256);
    const size_t oIR  = take(MAXITEMS * 4);
    const size_t oIE  = take(MAXITEMS * 4);
    const size_t oIX  = take(MAXITEMS * 4);
    const size_t oIN  = take(MAXITEMS * 4);
    (void)ws_size; (void)in_sizes; (void)n_in; (void)out_size;

    uint16_t* xbf  = (uint16_t*)(ws + oXBF);
    uint16_t* act  = (uint16_t*)(ws + oACT);
    uint16_t* ash  = (uint16_t*)(ws + oASH);
    uint16_t* w1t  = (uint16_t*)(ws + oW1T);
    uint16_t* ybuf = (uint16_t*)(ws + oW1T);
    uint16_t* w2t  = (uint16_t*)(ws + oW2T);
    uint16_t* s1t  = (uint16_t*)(ws + oS1T);
    uint16_t* s2t  = (uint16_t*)(ws + oS2T);
    int*   tki  = (int*)(ws + oTKI);
    float* tkw  = (float*)(ws + oTKW);
    int*   slot = (int*)(ws + oSLT);
    int*   prm  = (int*)(ws + oPRM);
    int*   ctl  = (int*)(ws + oCTL);
    int*   ofs  = (int*)(ws + oOFS);
    int*   cur  = (int*)(ws + oCUR);
    int*   nt   = (int*)(ws + oNT);
    int*   ir0  = (int*)(ws + oIR);
    int*   iend = (int*)(ws + oIE);
    int*   ie   = (int*)(ws + oIX);
    int*   in0  = (int*)(ws + oIN);

    hipMemsetAsync(ws + oCTL, 0, 1024, stream);

    k_router<<<T_TOK / 16, 256, 0, stream>>>(x, gw, eb, tki, tkw, ctl);
    k_scan2<<<1, 64, 0, stream>>>(ctl, ofs, cur, ir0, iend, ie, in0, nt);
    k_scatter<<<TKTOT / 256, 256, 0, stream>>>(tki, cur, prm, slot);

    k_cvt_bf16<<<(T_TOK * HDIM / 4 + 255) / 256, 256, 0, stream>>>(x, xbf, (long)T_TOK * HDIM / 4);
    k_transpose2<true ><<<dim3(32, 32, NEXP), 256, 0, stream>>>(w1, w1t, 2048, 2048,
        (long)2048 * 2048, (long)2048 * 2048);
    k_transpose2<false><<<dim3(32, 16, NEXP), 256, 0, stream>>>(w2, w2t, 1024, 2048,
        (long)1024 * 2048, (long)2048 * 1024);
    k_transpose2<true ><<<dim3(32, 32, 1), 256, 0, stream>>>(s1, s1t, 2048, 2048, 0, 0);
    k_transpose2<false><<<dim3(32, 16, 1), 256, 0, stream>>>(s2, s2t, 1024, 2048, 0, 0);

    // shared expert gate_up (+silu*mul) -> ash   (32 M-tiles x 8 panels = 256 blocks)
    k_gemm3<true, false><<<dim3(256), 512, 0, stream>>>(
        xbf, s1t, ash, nullptr, nullptr, nullptr, nullptr, nullptr, nullptr, nullptr, 2048, 0);
    // routed gate_up (+silu*mul) -> act   (persistent queue q0)
    k_gemm3<true, true><<<dim3(256), 512, 0, stream>>>(
        xbf, w1t, act, prm, ir0, iend, ie, in0, nt, ctl + 64, 2048, (long)2048 * 2048);
    // shared down -> d_out (f32)
    k_gemm3<false, false><<<dim3(256), 512, 0, stream>>>(
        ash, s2t, out, nullptr, nullptr, nullptr, nullptr, nullptr, nullptr, nullptr, 1024, 0);
    // routed down -> ybuf (bf16, aliases w1t; queue q1)
    k_gemm3<false, true><<<dim3(256), 512, 0, stream>>>(
        act, w2t, ybuf, nullptr, ir0, iend, ie, in0, nt, ctl + 65, 1024, (long)2048 * 1024);

    k_combine<<<T_TOK, 256, 0, stream>>>(out, ybuf, slot, tkw);
}